// Round 1
// 1513.466 us; speedup vs baseline: 1.4563x; 1.4563x over previous
//
#include <hip/hip_runtime.h>

typedef unsigned short bf16_t;
typedef uint4  __attribute__((may_alias)) uint4_a;
typedef uint2  __attribute__((may_alias)) uint2_a;
typedef float4 __attribute__((may_alias)) float4_a;
typedef short bf16x8 __attribute__((ext_vector_type(8)));
typedef bf16x8 __attribute__((may_alias)) bf16x8_a;
typedef float f32x4 __attribute__((ext_vector_type(4)));

#define MFMA16(a, b, c) __builtin_amdgcn_mfma_f32_16x16x32_bf16((a), (b), (c), 0, 0, 0)

constexpr int kS  = 256;
constexpr int kR  = 384;
constexpr int kCM = 256;
constexpr int kCZ = 128;
constexpr int kC  = 32;
constexpr int kH  = 8;
constexpr int kP  = kR * kR;        // 147456
constexpr int kM  = kS * kR;        // 98304

#define EPSF 1e-5f
#define SCALEF 0.17677669529663687f

__device__ __forceinline__ float bf2f(bf16_t u) {
  return __uint_as_float(((unsigned int)u) << 16);
}
__device__ __forceinline__ bf16_t f2bf(float f) {
  unsigned int u = __float_as_uint(f);
  u += 0x7fffu + ((u >> 16) & 1u);
  return (bf16_t)(u >> 16);
}

// ---------------- pair: stats + fp32->bf16 convert, fused, vectorized ----------------
// 8 rows per 256-thread block; 32 lanes per row, float4 per lane.
__global__ __launch_bounds__(256) void k_pair_fused(const float* __restrict__ pair,
                                                    bf16_t* __restrict__ pair_bf,
                                                    float* __restrict__ mu,
                                                    float* __restrict__ rstd) {
  int row = blockIdx.x * 8 + (threadIdx.x >> 5);
  int l = threadIdx.x & 31;
  const float* src = pair + (size_t)row * kCZ + l * 4;
  float4_a x = *(const float4_a*)src;
  float s1 = x.x + x.y + x.z + x.w;
  float s2 = x.x * x.x + x.y * x.y + x.z * x.z + x.w * x.w;
#pragma unroll
  for (int off = 16; off > 0; off >>= 1) {
    s1 += __shfl_xor(s1, off);
    s2 += __shfl_xor(s2, off);
  }
  float m = s1 * (1.0f / kCZ);
  float v = s2 * (1.0f / kCZ) - m * m;
  float rs = rsqrtf(fmaxf(v, 0.0f) + EPSF);
  if (l == 0) {
    mu[row] = m;
    rstd[row] = rs;
  }
  uint2 u;
  u.x = (unsigned)f2bf(x.x) | ((unsigned)f2bf(x.y) << 16);
  u.y = (unsigned)f2bf(x.z) | ((unsigned)f2bf(x.w) << 16);
  *(uint2_a*)(pair_bf + (size_t)row * kCZ + l * 4) = u;
}

// ---------------- msa LN (fp32/bf16 src -> bf16 dst), vectorized ----------------
// 8 rows per 256-thread block; 32 lanes per row, 8 elems per lane.
__global__ __launch_bounds__(256) void k_msa_ln(const float* __restrict__ src_f,
                                                const bf16_t* __restrict__ src_b,
                                                bf16_t* __restrict__ dst,
                                                const float* __restrict__ wall,
                                                const float* __restrict__ ball,
                                                int head, int first) {
  int row = blockIdx.x * 8 + (threadIdx.x >> 5);
  int l = threadIdx.x & 31;
  int c0 = l * 8;
  float x[8];
  if (first) {
    float4_a a = *(const float4_a*)(src_f + (size_t)row * kCM + c0);
    float4_a b = *(const float4_a*)(src_f + (size_t)row * kCM + c0 + 4);
    x[0] = a.x; x[1] = a.y; x[2] = a.z; x[3] = a.w;
    x[4] = b.x; x[5] = b.y; x[6] = b.z; x[7] = b.w;
  } else {
    union { bf16x8 v; bf16_t h[8]; } uu;
    uu.v = *(const bf16x8_a*)(src_b + (size_t)row * kCM + c0);
#pragma unroll
    for (int j = 0; j < 8; ++j) x[j] = bf2f(uu.h[j]);
  }
  float s1 = 0.f, s2 = 0.f;
#pragma unroll
  for (int j = 0; j < 8; ++j) {
    s1 += x[j];
    s2 += x[j] * x[j];
  }
#pragma unroll
  for (int off = 16; off > 0; off >>= 1) {
    s1 += __shfl_xor(s1, off);
    s2 += __shfl_xor(s2, off);
  }
  float m = s1 * (1.0f / kCM);
  float var = s2 * (1.0f / kCM) - m * m;
  float rs = rsqrtf(fmaxf(var, 0.0f) + EPSF);
  float4_a wa = *(const float4_a*)(wall + head * kCM + c0);
  float4_a wb4 = *(const float4_a*)(wall + head * kCM + c0 + 4);
  float4_a ba = *(const float4_a*)(ball + head * kCM + c0);
  float4_a bb4 = *(const float4_a*)(ball + head * kCM + c0 + 4);
  float wv[8] = {wa.x, wa.y, wa.z, wa.w, wb4.x, wb4.y, wb4.z, wb4.w};
  float bv[8] = {ba.x, ba.y, ba.z, ba.w, bb4.x, bb4.y, bb4.z, bb4.w};
  bf16_t h[8];
#pragma unroll
  for (int j = 0; j < 8; ++j) h[j] = f2bf((x[j] - m) * rs * wv[j] + bv[j]);
  uint4 u;
  u.x = (unsigned)h[0] | ((unsigned)h[1] << 16);
  u.y = (unsigned)h[2] | ((unsigned)h[3] << 16);
  u.z = (unsigned)h[4] | ((unsigned)h[5] << 16);
  u.w = (unsigned)h[6] | ((unsigned)h[7] << 16);
  *(uint4_a*)(dst + (size_t)row * kCM + c0) = u;
}

// ---------------- pack qkvg weights for ALL heads -> bf16 (H x 128 x 256) ----------------
__global__ __launch_bounds__(256) void k_pack_wcat_all(const float* __restrict__ wq,
                                                       const float* __restrict__ wk,
                                                       const float* __restrict__ wv,
                                                       const float* __restrict__ wg,
                                                       bf16_t* __restrict__ Wcat) {
  int gid = blockIdx.x * 256 + threadIdx.x;  // 0..262143
  int head = gid >> 15;
  int idx = gid & 32767;
  int j = idx >> 8;
  int c = idx & 255;
  const float* src = (j < 32) ? wq : (j < 64) ? wk : (j < 96) ? wv : wg;
  int d = j & 31;
  Wcat[gid] = f2bf(src[(head * kC + d) * kCM + c]);
}

// ---------------- pack bias weights (pair-LN folded) for ALL heads -> bf16 ----------------
__global__ __launch_bounds__(256) void k_pack_bias_all(const float* __restrict__ wb,
                                                       const float* __restrict__ npw,
                                                       const float* __restrict__ npb,
                                                       bf16_t* __restrict__ wbeff,
                                                       float* __restrict__ beta,
                                                       float* __restrict__ sw) {
  int head = blockIdx.x;
  int j = threadIdx.x;  // 256 threads
  float sb = 0.f, ssw = 0.f;
  for (int c = 0; c < kCZ; ++c) {
    float w = wb[(head * kS + j) * kCZ + c];
    float e = w * npw[head * kCZ + c];
    wbeff[(size_t)head * kS * kCZ + j * kCZ + c] = f2bf(e);
    ssw += e;
    sb += w * npb[head * kCZ + c];
  }
  sw[head * kS + j] = ssw;
  beta[head * kS + j] = sb;
}

// ---------------- pack out_w -> bf16 ----------------
__global__ __launch_bounds__(256) void k_pack_outw(const float* __restrict__ in,
                                                   bf16_t* __restrict__ out) {
  int i = blockIdx.x * 256 + threadIdx.x;  // 65536
  out[i] = f2bf(in[i]);
}

// ---------------- qkvg GEMM MFMA: (kM x 256) x (128 x 256)^T ----------------
__global__ __launch_bounds__(256) void k_gemm_qkvg_mx(const bf16_t* __restrict__ A,
                                                      const bf16_t* __restrict__ B,
                                                      bf16_t* __restrict__ q,
                                                      bf16_t* __restrict__ k,
                                                      bf16_t* __restrict__ v,
                                                      bf16_t* __restrict__ g) {
  __shared__ bf16_t As[128 * 32];
  __shared__ bf16_t Bs[128 * 32];
  int m0 = blockIdx.x * 128;
  int tid = threadIdx.x;
  int w = tid >> 6, L = tid & 63, l15 = L & 15, q4 = L >> 4;
  int wm = w >> 1, wn = w & 1;
  f32x4 acc[4][4] = {};
  for (int k0 = 0; k0 < 256; k0 += 32) {
#pragma unroll
    for (int rep = 0; rep < 2; ++rep) {
      int idx = tid + rep * 256;
      int row = idx >> 2, sg = idx & 3;
      *(uint4_a*)&As[row * 32 + sg * 8] = *(const uint4_a*)(A + (size_t)(m0 + row) * 256 + k0 + sg * 8);
      *(uint4_a*)&Bs[row * 32 + sg * 8] = *(const uint4_a*)(B + (size_t)row * 256 + k0 + sg * 8);
    }
    __syncthreads();
    bf16x8 af[4], bfr[4];
#pragma unroll
    for (int mt = 0; mt < 4; ++mt) af[mt] = *(const bf16x8_a*)&As[(wm * 64 + mt * 16 + l15) * 32 + q4 * 8];
#pragma unroll
    for (int nt = 0; nt < 4; ++nt) bfr[nt] = *(const bf16x8_a*)&Bs[(wn * 64 + nt * 16 + l15) * 32 + q4 * 8];
#pragma unroll
    for (int mt = 0; mt < 4; ++mt)
#pragma unroll
      for (int nt = 0; nt < 4; ++nt) acc[mt][nt] = MFMA16(af[mt], bfr[nt], acc[mt][nt]);
    __syncthreads();
  }
#pragma unroll
  for (int mt = 0; mt < 4; ++mt)
#pragma unroll
    for (int nt = 0; nt < 4; ++nt) {
      int n = wn * 64 + nt * 16 + l15;
      int mat = n >> 5, d = n & 31;
      bf16_t* tgt = (mat == 0) ? q : (mat == 1) ? k : (mat == 2) ? v : g;
#pragma unroll
      for (int i = 0; i < 4; ++i) {
        int m = m0 + wm * 64 + mt * 16 + q4 * 4 + i;
        float val = acc[mt][nt][i];
        if (mat == 3) val = 1.0f / (1.0f + __expf(-val));
        tgt[(size_t)m * kC + d] = f2bf(val);
      }
    }
}

// ---------------- bias GEMM MFMA: (kP x 128) x (256 x 128)^T -> Bm bf16 ----------------
__global__ __launch_bounds__(256) void k_gemm_bias_mx(const bf16_t* __restrict__ A,
                                                      const bf16_t* __restrict__ B,
                                                      const float* __restrict__ mu,
                                                      const float* __restrict__ rstd,
                                                      const float* __restrict__ sw,
                                                      const float* __restrict__ beta,
                                                      bf16_t* __restrict__ Bm) {
  __shared__ bf16_t As[128 * 32];
  __shared__ bf16_t Bs[128 * 32];
  int m0 = blockIdx.x * 128;
  int n0 = blockIdx.y * 128;
  int tid = threadIdx.x;
  int w = tid >> 6, L = tid & 63, l15 = L & 15, q4 = L >> 4;
  int wm = w >> 1, wn = w & 1;
  f32x4 acc[4][4] = {};
  for (int k0 = 0; k0 < 128; k0 += 32) {
#pragma unroll
    for (int rep = 0; rep < 2; ++rep) {
      int idx = tid + rep * 256;
      int row = idx >> 2, sg = idx & 3;
      *(uint4_a*)&As[row * 32 + sg * 8] = *(const uint4_a*)(A + (size_t)(m0 + row) * 128 + k0 + sg * 8);
      *(uint4_a*)&Bs[row * 32 + sg * 8] = *(const uint4_a*)(B + (size_t)(n0 + row) * 128 + k0 + sg * 8);
    }
    __syncthreads();
    bf16x8 af[4], bfr[4];
#pragma unroll
    for (int mt = 0; mt < 4; ++mt) af[mt] = *(const bf16x8_a*)&As[(wm * 64 + mt * 16 + l15) * 32 + q4 * 8];
#pragma unroll
    for (int nt = 0; nt < 4; ++nt) bfr[nt] = *(const bf16x8_a*)&Bs[(wn * 64 + nt * 16 + l15) * 32 + q4 * 8];
#pragma unroll
    for (int mt = 0; mt < 4; ++mt)
#pragma unroll
      for (int nt = 0; nt < 4; ++nt) acc[mt][nt] = MFMA16(af[mt], bfr[nt], acc[mt][nt]);
    __syncthreads();
  }
#pragma unroll
  for (int mt = 0; mt < 4; ++mt)
#pragma unroll
    for (int i = 0; i < 4; ++i) {
      int m = m0 + wm * 64 + mt * 16 + q4 * 4 + i;
      float mp = mu[m], rp = rstd[m];
#pragma unroll
      for (int nt = 0; nt < 4; ++nt) {
        int n = n0 + wn * 64 + nt * 16 + l15;
        float val = rp * (acc[mt][nt][i] - mp * sw[n]) + beta[n];
        Bm[(size_t)m * kS + n] = f2bf(val);
      }
    }
}

// ---------------- logits: QK^T MFMA + bias (in acc) + column softmax -> a (in-place Bm) ----------------
__global__ __launch_bounds__(256) void k_logits(const bf16_t* __restrict__ q,
                                                const bf16_t* __restrict__ kmat,
                                                bf16_t* __restrict__ Bm) {
  int s = blockIdx.y;
  int t0 = blockIdx.x * 64;
  int tid = threadIdx.x;
  int w = tid >> 6, L = tid & 63, l15 = L & 15, q4 = L >> 4;
  __shared__ float red[4][64];
  __shared__ float msh[64], dish[64];
  bf16_t* bmS = Bm + (size_t)s * kP;
  f32x4 acc[6][4];
  // preload bias into accumulator (C/D layout)
#pragma unroll
  for (int rt = 0; rt < 6; ++rt)
#pragma unroll
    for (int nt = 0; nt < 4; ++nt)
#pragma unroll
      for (int i = 0; i < 4; ++i) {
        int r = w * 96 + rt * 16 + q4 * 4 + i;
        int t = t0 + nt * 16 + l15;
        acc[rt][nt][i] = bf2f(bmS[(size_t)r * kR + t]);
      }
  const bf16_t* qs = q + (size_t)s * kR * kC;
  const bf16_t* ks = kmat + (size_t)s * kR * kC;
  bf16x8 bfr[4];
#pragma unroll
  for (int nt = 0; nt < 4; ++nt)
    bfr[nt] = *(const bf16x8_a*)(ks + (size_t)(t0 + nt * 16 + l15) * kC + q4 * 8);
#pragma unroll
  for (int rt = 0; rt < 6; ++rt) {
    bf16x8 af = *(const bf16x8_a*)(qs + (size_t)(w * 96 + rt * 16 + l15) * kC + q4 * 8);
#pragma unroll
    for (int nt = 0; nt < 4; ++nt) acc[rt][nt] = MFMA16(af, bfr[nt], acc[rt][nt]);
  }
  // scale
#pragma unroll
  for (int rt = 0; rt < 6; ++rt)
#pragma unroll
    for (int nt = 0; nt < 4; ++nt) acc[rt][nt] *= SCALEF;
  // column (over r) max
  float mx[4] = {-3.0e38f, -3.0e38f, -3.0e38f, -3.0e38f};
#pragma unroll
  for (int rt = 0; rt < 6; ++rt)
#pragma unroll
    for (int nt = 0; nt < 4; ++nt)
#pragma unroll
      for (int i = 0; i < 4; ++i) mx[nt] = fmaxf(mx[nt], acc[rt][nt][i]);
#pragma unroll
  for (int nt = 0; nt < 4; ++nt) {
    mx[nt] = fmaxf(mx[nt], __shfl_xor(mx[nt], 16));
    mx[nt] = fmaxf(mx[nt], __shfl_xor(mx[nt], 32));
  }
  if (L < 16) {
#pragma unroll
    for (int nt = 0; nt < 4; ++nt) red[w][nt * 16 + L] = mx[nt];
  }
  __syncthreads();
  if (tid < 64) {
    float m = fmaxf(fmaxf(red[0][tid], red[1][tid]), fmaxf(red[2][tid], red[3][tid]));
    msh[tid] = m;
  }
  __syncthreads();
  float mt_[4];
#pragma unroll
  for (int nt = 0; nt < 4; ++nt) mt_[nt] = msh[nt * 16 + l15];
  float sm[4] = {0.f, 0.f, 0.f, 0.f};
#pragma unroll
  for (int rt = 0; rt < 6; ++rt)
#pragma unroll
    for (int nt = 0; nt < 4; ++nt)
#pragma unroll
      for (int i = 0; i < 4; ++i) {
        float e = __expf(acc[rt][nt][i] - mt_[nt]);
        acc[rt][nt][i] = e;
        sm[nt] += e;
      }
#pragma unroll
  for (int nt = 0; nt < 4; ++nt) {
    sm[nt] += __shfl_xor(sm[nt], 16);
    sm[nt] += __shfl_xor(sm[nt], 32);
  }
  __syncthreads();
  if (L < 16) {
#pragma unroll
    for (int nt = 0; nt < 4; ++nt) red[w][nt * 16 + L] = sm[nt];
  }
  __syncthreads();
  if (tid < 64) {
    float d = red[0][tid] + red[1][tid] + red[2][tid] + red[3][tid];
    dish[tid] = 1.0f / d;
  }
  __syncthreads();
  float di[4];
#pragma unroll
  for (int nt = 0; nt < 4; ++nt) di[nt] = dish[nt * 16 + l15];
  // write probabilities a (bf16) in place
#pragma unroll
  for (int rt = 0; rt < 6; ++rt)
#pragma unroll
    for (int nt = 0; nt < 4; ++nt)
#pragma unroll
      for (int i = 0; i < 4; ++i) {
        int r = w * 96 + rt * 16 + q4 * 4 + i;
        int t = t0 + nt * 16 + l15;
        bmS[(size_t)r * kR + t] = f2bf(acc[rt][nt][i] * di[nt]);
      }
}

// ---------------- PV: o = g * (a @ v) via MFMA, fp32 out into d_out slice ----------------
__global__ __launch_bounds__(256) void k_pv(const bf16_t* __restrict__ Am,
                                            const bf16_t* __restrict__ v,
                                            const bf16_t* __restrict__ g,
                                            float* __restrict__ o, int head) {
  int s = blockIdx.y;
  int r0 = blockIdx.x * 64;
  int tid = threadIdx.x;
  int w = tid >> 6, L = tid & 63, l15 = L & 15, q4 = L >> 4;
  __shared__ bf16_t vT[32 * 392];  // [c][t], padded stride
  // stage v transposed
#pragma unroll
  for (int rep = 0; rep < 6; ++rep) {
    int idx = tid + rep * 256;  // 1536
    int t = idx >> 2, sg = idx & 3;
    union { uint4 u; bf16_t h[8]; } uu;
    uu.u = *(const uint4_a*)(v + (size_t)(s * kR + t) * kC + sg * 8);
#pragma unroll
    for (int j = 0; j < 8; ++j) vT[(sg * 8 + j) * 392 + t] = uu.h[j];
  }
  __syncthreads();
  const bf16_t* aS = Am + (size_t)s * kP + (size_t)(r0 + 16 * w + l15) * kR;
  f32x4 acc[2] = {};
#pragma unroll
  for (int kk = 0; kk < 12; ++kk) {
    bf16x8 af = *(const bf16x8_a*)(aS + kk * 32 + q4 * 8);
#pragma unroll
    for (int nt = 0; nt < 2; ++nt) {
      bf16x8 bfv = *(const bf16x8_a*)&vT[(nt * 16 + l15) * 392 + kk * 32 + q4 * 8];
      acc[nt] = MFMA16(af, bfv, acc[nt]);
    }
  }
#pragma unroll
  for (int nt = 0; nt < 2; ++nt)
#pragma unroll
    for (int i = 0; i < 4; ++i) {
      int r = r0 + 16 * w + q4 * 4 + i;
      int c = nt * 16 + l15;
      float val = acc[nt][i] * bf2f(g[(size_t)(s * kR + r) * kC + c]);
      o[(size_t)(s * kR + r) * kCM + head * kC + c] = val;
    }
}

// ---------------- final GEMM: (kM x 256 fp32 -> hi/lo bf16) x (256 x 256)^T bf16, in-place d_out ----------------
__global__ __launch_bounds__(256) void k_gemm_final_mx(const float* __restrict__ OA,
                                                       const bf16_t* __restrict__ Bw,
                                                       const float* __restrict__ bias,
                                                       float* __restrict__ out) {
  __shared__ bf16_t As[2 * 64 * 32];  // [half][row][k]
  __shared__ bf16_t Bs[256 * 32];
  int m0 = blockIdx.x * 64;
  int tid = threadIdx.x;
  int w = tid >> 6, L = tid & 63, l15 = L & 15, q4 = L >> 4;
  f32x4 acc[4][4] = {};  // [mt][nt]
  for (int kc = 0; kc < 256; kc += 32) {
    {
      int row = tid >> 2, sg = tid & 3;
      const float* src = OA + (size_t)(m0 + row) * kCM + kc + sg * 8;
      float4_a f0 = *(const float4_a*)src;
      float4_a f1 = *(const float4_a*)(src + 4);
      float ff[8] = {f0.x, f0.y, f0.z, f0.w, f1.x, f1.y, f1.z, f1.w};
      uint4 uh, ul;
      bf16_t hi[8], lo[8];
#pragma unroll
      for (int j = 0; j < 8; ++j) {
        hi[j] = f2bf(ff[j]);
        lo[j] = f2bf(ff[j] - bf2f(hi[j]));
      }
      uh.x = (unsigned)hi[0] | ((unsigned)hi[1] << 16); uh.y = (unsigned)hi[2] | ((unsigned)hi[3] << 16);
      uh.z = (unsigned)hi[4] | ((unsigned)hi[5] << 16); uh.w = (unsigned)hi[6] | ((unsigned)hi[7] << 16);
      ul.x = (unsigned)lo[0] | ((unsigned)lo[1] << 16); ul.y = (unsigned)lo[2] | ((unsigned)lo[3] << 16);
      ul.z = (unsigned)lo[4] | ((unsigned)lo[5] << 16); ul.w = (unsigned)lo[6] | ((unsigned)lo[7] << 16);
      *(uint4_a*)&As[row * 32 + sg * 8] = uh;
      *(uint4_a*)&As[2048 + row * 32 + sg * 8] = ul;
    }
#pragma unroll
    for (int rep = 0; rep < 4; ++rep) {
      int idx = tid + rep * 256;
      int row = idx >> 2, sg = idx & 3;
      *(uint4_a*)&Bs[row * 32 + sg * 8] = *(const uint4_a*)(Bw + (size_t)row * kCM + kc + sg * 8);
    }
    __syncthreads();
    bf16x8 bfr[4];
#pragma unroll
    for (int nt = 0; nt < 4; ++nt) bfr[nt] = *(const bf16x8_a*)&Bs[(w * 64 + nt * 16 + l15) * 32 + q4 * 8];
#pragma unroll
    for (int half = 0; half < 2; ++half)
#pragma unroll
      for (int mt = 0; mt < 4; ++mt) {
        bf16x8 af = *(const bf16x8_a*)&As[half * 2048 + (mt * 16 + l15) * 32 + q4 * 8];
#pragma unroll
        for (int nt = 0; nt < 4; ++nt) acc[mt][nt] = MFMA16(af, bfr[nt], acc[mt][nt]);
      }
    __syncthreads();
  }
#pragma unroll
  for (int mt = 0; mt < 4; ++mt)
#pragma unroll
    for (int nt = 0; nt < 4; ++nt) {
      int n = w * 64 + nt * 16 + l15;
      float bn = bias[n];
#pragma unroll
      for (int i = 0; i < 4; ++i) {
        int m = m0 + mt * 16 + q4 * 4 + i;
        out[(size_t)m * kCM + n] = acc[mt][nt][i] + bn;
      }
    }
}

extern "C" void kernel_launch(void* const* d_in, const int* in_sizes, int n_in,
                              void* d_out, int out_size, void* d_ws, size_t ws_size,
                              hipStream_t stream) {
  (void)in_sizes; (void)n_in; (void)out_size; (void)ws_size;
  const float* msa_in = (const float*)d_in[0];
  const float* pair   = (const float*)d_in[1];
  const float* nmw    = (const float*)d_in[2];
  const float* nmb    = (const float*)d_in[3];
  const float* wq     = (const float*)d_in[4];
  const float* wk     = (const float*)d_in[5];
  const float* wv     = (const float*)d_in[6];
  const float* npw    = (const float*)d_in[7];
  const float* npb    = (const float*)d_in[8];
  const float* wb     = (const float*)d_in[9];
  const float* wg     = (const float*)d_in[10];
  const float* outw   = (const float*)d_in[11];
  const float* outb   = (const float*)d_in[12];
  float* out = (float*)d_out;

  char* ws = (char*)d_ws;
  size_t off = 0;
  bf16_t* msa_cur  = (bf16_t*)(ws + off); off += (size_t)kM * kCM * 2;    // 50,331,648
  bf16_t* pair_bf  = (bf16_t*)(ws + off); off += (size_t)kP * kCZ * 2;    // 37,748,736
  bf16_t* Bm       = (bf16_t*)(ws + off); off += (size_t)kP * kS * 2;     // 75,497,472 (full)
  bf16_t* qb       = (bf16_t*)(ws + off); off += (size_t)kM * kC * 2;     // 6,291,456
  bf16_t* kb       = (bf16_t*)(ws + off); off += (size_t)kM * kC * 2;
  bf16_t* vb       = (bf16_t*)(ws + off); off += (size_t)kM * kC * 2;
  bf16_t* gb       = (bf16_t*)(ws + off); off += (size_t)kM * kC * 2;
  float* mu_p      = (float*)(ws + off);  off += (size_t)kP * 4;          // 589,824
  float* rstd_p    = (float*)(ws + off);  off += (size_t)kP * 4;
  bf16_t* Wcat_all = (bf16_t*)(ws + off); off += (size_t)kH * 128 * 256 * 2;
  bf16_t* wbef_all = (bf16_t*)(ws + off); off += (size_t)kH * 256 * 128 * 2;
  bf16_t* outw_bf  = (bf16_t*)(ws + off); off += (size_t)256 * 256 * 2;
  float* beta_all  = (float*)(ws + off);  off += (size_t)kH * 256 * 4;
  float* sw_all    = (float*)(ws + off);  off += (size_t)kH * 256 * 4;
  // total ~191 MB (fill evidence: ws buffer is 384 MiB)

  // setup (off the per-head critical path)
  k_pair_fused<<<kP / 8, 256, 0, stream>>>(pair, pair_bf, mu_p, rstd_p);
  k_pack_outw<<<256, 256, 0, stream>>>(outw, outw_bf);
  k_pack_wcat_all<<<kH * 128, 256, 0, stream>>>(wq, wk, wv, wg, Wcat_all);
  k_pack_bias_all<<<kH, 256, 0, stream>>>(wb, npw, npb, wbef_all, beta_all, sw_all);

  for (int h = 0; h < kH; ++h) {
    k_msa_ln<<<kM / 8, 256, 0, stream>>>(msa_in, msa_cur, msa_cur, nmw, nmb, h, h == 0 ? 1 : 0);
    k_gemm_qkvg_mx<<<kM / 128, 256, 0, stream>>>(msa_cur, Wcat_all + (size_t)h * 128 * 256,
                                                 qb, kb, vb, gb);
    k_gemm_bias_mx<<<dim3(kP / 128, 2), 256, 0, stream>>>(pair_bf, wbef_all + (size_t)h * 256 * 128,
                                                          mu_p, rstd_p,
                                                          sw_all + h * 256, beta_all + h * 256, Bm);
    k_logits<<<dim3(6, kS), 256, 0, stream>>>(qb, kb, Bm);
    k_pv<<<dim3(6, kS), 256, 0, stream>>>(Bm, vb, gb, out, h);
  }

  k_gemm_final_mx<<<kM / 64, 256, 0, stream>>>(out, outw_bf, outb, out);
}

// Round 3
// 1324.666 us; speedup vs baseline: 1.6639x; 1.1425x over previous
//
#include <hip/hip_runtime.h>

typedef unsigned short bf16_t;
typedef uint4  __attribute__((may_alias)) uint4_a;
typedef uint2  __attribute__((may_alias)) uint2_a;
typedef float4 __attribute__((may_alias)) float4_a;
typedef short bf16x8 __attribute__((ext_vector_type(8)));
typedef bf16x8 __attribute__((may_alias)) bf16x8_a;
typedef float f32x4 __attribute__((ext_vector_type(4)));

#define MFMA16(a, b, c) __builtin_amdgcn_mfma_f32_16x16x32_bf16((a), (b), (c), 0, 0, 0)

constexpr int kS  = 256;
constexpr int kR  = 384;
constexpr int kCM = 256;
constexpr int kCZ = 128;
constexpr int kC  = 32;
constexpr int kH  = 8;
constexpr int kP  = kR * kR;        // 147456
constexpr int kM  = kS * kR;        // 98304

#define EPSF 1e-5f
#define SCALEF 0.17677669529663687f

__device__ __forceinline__ float bf2f(bf16_t u) {
  return __uint_as_float(((unsigned int)u) << 16);
}
__device__ __forceinline__ bf16_t f2bf(float f) {
  unsigned int u = __float_as_uint(f);
  u += 0x7fffu + ((u >> 16) & 1u);
  return (bf16_t)(u >> 16);
}

// ---------------- pair: stats + fp32->bf16 convert, fused, vectorized ----------------
__global__ __launch_bounds__(256) void k_pair_fused(const float* __restrict__ pair,
                                                    bf16_t* __restrict__ pair_bf,
                                                    float* __restrict__ mu,
                                                    float* __restrict__ rstd) {
  int row = blockIdx.x * 8 + (threadIdx.x >> 5);
  int l = threadIdx.x & 31;
  const float* src = pair + (size_t)row * kCZ + l * 4;
  float4_a x = *(const float4_a*)src;
  float s1 = x.x + x.y + x.z + x.w;
  float s2 = x.x * x.x + x.y * x.y + x.z * x.z + x.w * x.w;
#pragma unroll
  for (int off = 16; off > 0; off >>= 1) {
    s1 += __shfl_xor(s1, off);
    s2 += __shfl_xor(s2, off);
  }
  float m = s1 * (1.0f / kCZ);
  float v = s2 * (1.0f / kCZ) - m * m;
  float rs = rsqrtf(fmaxf(v, 0.0f) + EPSF);
  if (l == 0) {
    mu[row] = m;
    rstd[row] = rs;
  }
  uint2 u;
  u.x = (unsigned)f2bf(x.x) | ((unsigned)f2bf(x.y) << 16);
  u.y = (unsigned)f2bf(x.z) | ((unsigned)f2bf(x.w) << 16);
  *(uint2_a*)(pair_bf + (size_t)row * kCZ + l * 4) = u;
}

// ---------------- msa LN (fp32/bf16 src -> bf16 dst), vectorized ----------------
__global__ __launch_bounds__(256) void k_msa_ln(const float* __restrict__ src_f,
                                                const bf16_t* __restrict__ src_b,
                                                bf16_t* __restrict__ dst,
                                                const float* __restrict__ wall,
                                                const float* __restrict__ ball,
                                                int head, int first) {
  int row = blockIdx.x * 8 + (threadIdx.x >> 5);
  int l = threadIdx.x & 31;
  int c0 = l * 8;
  float x[8];
  if (first) {
    float4_a a = *(const float4_a*)(src_f + (size_t)row * kCM + c0);
    float4_a b = *(const float4_a*)(src_f + (size_t)row * kCM + c0 + 4);
    x[0] = a.x; x[1] = a.y; x[2] = a.z; x[3] = a.w;
    x[4] = b.x; x[5] = b.y; x[6] = b.z; x[7] = b.w;
  } else {
    union { bf16x8 v; bf16_t h[8]; } uu;
    uu.v = *(const bf16x8_a*)(src_b + (size_t)row * kCM + c0);
#pragma unroll
    for (int j = 0; j < 8; ++j) x[j] = bf2f(uu.h[j]);
  }
  float s1 = 0.f, s2 = 0.f;
#pragma unroll
  for (int j = 0; j < 8; ++j) {
    s1 += x[j];
    s2 += x[j] * x[j];
  }
#pragma unroll
  for (int off = 16; off > 0; off >>= 1) {
    s1 += __shfl_xor(s1, off);
    s2 += __shfl_xor(s2, off);
  }
  float m = s1 * (1.0f / kCM);
  float var = s2 * (1.0f / kCM) - m * m;
  float rs = rsqrtf(fmaxf(var, 0.0f) + EPSF);
  float4_a wa = *(const float4_a*)(wall + head * kCM + c0);
  float4_a wb4 = *(const float4_a*)(wall + head * kCM + c0 + 4);
  float4_a ba = *(const float4_a*)(ball + head * kCM + c0);
  float4_a bb4 = *(const float4_a*)(ball + head * kCM + c0 + 4);
  float wv[8] = {wa.x, wa.y, wa.z, wa.w, wb4.x, wb4.y, wb4.z, wb4.w};
  float bv[8] = {ba.x, ba.y, ba.z, ba.w, bb4.x, bb4.y, bb4.z, bb4.w};
  bf16_t h[8];
#pragma unroll
  for (int j = 0; j < 8; ++j) h[j] = f2bf((x[j] - m) * rs * wv[j] + bv[j]);
  uint4 u;
  u.x = (unsigned)h[0] | ((unsigned)h[1] << 16);
  u.y = (unsigned)h[2] | ((unsigned)h[3] << 16);
  u.z = (unsigned)h[4] | ((unsigned)h[5] << 16);
  u.w = (unsigned)h[6] | ((unsigned)h[7] << 16);
  *(uint4_a*)(dst + (size_t)row * kCM + c0) = u;
}

// ---------------- pack qkvg weights for ALL heads -> bf16 (H x 128 x 256) ----------------
__global__ __launch_bounds__(256) void k_pack_wcat_all(const float* __restrict__ wq,
                                                       const float* __restrict__ wk,
                                                       const float* __restrict__ wv,
                                                       const float* __restrict__ wg,
                                                       bf16_t* __restrict__ Wcat) {
  int gid = blockIdx.x * 256 + threadIdx.x;  // 0..262143
  int head = gid >> 15;
  int idx = gid & 32767;
  int j = idx >> 8;
  int c = idx & 255;
  const float* src = (j < 32) ? wq : (j < 64) ? wk : (j < 96) ? wv : wg;
  int d = j & 31;
  Wcat[gid] = f2bf(src[(head * kC + d) * kCM + c]);
}

// ---------------- pack bias weights (pair-LN + 1/sqrt(c) folded) for ALL heads ----------------
__global__ __launch_bounds__(256) void k_pack_bias_all(const float* __restrict__ wb,
                                                       const float* __restrict__ npw,
                                                       const float* __restrict__ npb,
                                                       bf16_t* __restrict__ wbeff,
                                                       float* __restrict__ beta,
                                                       float* __restrict__ sw) {
  int head = blockIdx.x;
  int j = threadIdx.x;  // 256 threads
  float sb = 0.f, ssw = 0.f;
  for (int c = 0; c < kCZ; ++c) {
    float w = wb[(head * kS + j) * kCZ + c];
    float e = w * npw[head * kCZ + c] * SCALEF;   // fold softmax scale
    wbeff[(size_t)head * kS * kCZ + j * kCZ + c] = f2bf(e);
    ssw += e;
    sb += w * npb[head * kCZ + c];
  }
  sw[head * kS + j] = ssw;
  beta[head * kS + j] = sb * SCALEF;
}

// ---------------- pack out_w -> bf16 ----------------
__global__ __launch_bounds__(256) void k_pack_outw(const float* __restrict__ in,
                                                   bf16_t* __restrict__ out) {
  int i = blockIdx.x * 256 + threadIdx.x;  // 65536
  out[i] = f2bf(in[i]);
}

// ---------------- qkvg GEMM MFMA: (kM x 256) x (128 x 256)^T ----------------
// q pre-scaled by 1/sqrt(c); g written into g_all[kM][256] at head slice.
__global__ __launch_bounds__(256) void k_gemm_qkvg_mx(const bf16_t* __restrict__ A,
                                                      const bf16_t* __restrict__ B,
                                                      bf16_t* __restrict__ q,
                                                      bf16_t* __restrict__ k,
                                                      bf16_t* __restrict__ v,
                                                      bf16_t* __restrict__ g_all,
                                                      int head) {
  __shared__ bf16_t As[128 * 32];
  __shared__ bf16_t Bs[128 * 32];
  int m0 = blockIdx.x * 128;
  int tid = threadIdx.x;
  int w = tid >> 6, L = tid & 63, l15 = L & 15, q4 = L >> 4;
  int wm = w >> 1, wn = w & 1;
  f32x4 acc[4][4] = {};
  for (int k0 = 0; k0 < 256; k0 += 32) {
#pragma unroll
    for (int rep = 0; rep < 2; ++rep) {
      int idx = tid + rep * 256;
      int row = idx >> 2, sg = idx & 3;
      *(uint4_a*)&As[row * 32 + sg * 8] = *(const uint4_a*)(A + (size_t)(m0 + row) * 256 + k0 + sg * 8);
      *(uint4_a*)&Bs[row * 32 + sg * 8] = *(const uint4_a*)(B + (size_t)row * 256 + k0 + sg * 8);
    }
    __syncthreads();
    bf16x8 af[4], bfr[4];
#pragma unroll
    for (int mt = 0; mt < 4; ++mt) af[mt] = *(const bf16x8_a*)&As[(wm * 64 + mt * 16 + l15) * 32 + q4 * 8];
#pragma unroll
    for (int nt = 0; nt < 4; ++nt) bfr[nt] = *(const bf16x8_a*)&Bs[(wn * 64 + nt * 16 + l15) * 32 + q4 * 8];
#pragma unroll
    for (int mt = 0; mt < 4; ++mt)
#pragma unroll
      for (int nt = 0; nt < 4; ++nt) acc[mt][nt] = MFMA16(af[mt], bfr[nt], acc[mt][nt]);
    __syncthreads();
  }
#pragma unroll
  for (int mt = 0; mt < 4; ++mt)
#pragma unroll
    for (int nt = 0; nt < 4; ++nt) {
      int n = wn * 64 + nt * 16 + l15;
      int mat = n >> 5, d = n & 31;
#pragma unroll
      for (int i = 0; i < 4; ++i) {
        int m = m0 + wm * 64 + mt * 16 + q4 * 4 + i;
        float val = acc[mt][nt][i];
        if (mat == 0) {
          q[(size_t)m * kC + d] = f2bf(val * SCALEF);
        } else if (mat == 1) {
          k[(size_t)m * kC + d] = f2bf(val);
        } else if (mat == 2) {
          v[(size_t)m * kC + d] = f2bf(val);
        } else {
          float sg = 1.0f / (1.0f + __expf(-val));
          g_all[(size_t)m * kCM + head * kC + d] = f2bf(sg);
        }
      }
    }
}

// ---------------- bias GEMM MFMA: (kP x 128) x (256 x 128)^T -> Bm bf16 (pre-scaled) ----------------
__global__ __launch_bounds__(256) void k_gemm_bias_mx(const bf16_t* __restrict__ A,
                                                      const bf16_t* __restrict__ B,
                                                      const float* __restrict__ mu,
                                                      const float* __restrict__ rstd,
                                                      const float* __restrict__ sw,
                                                      const float* __restrict__ beta,
                                                      bf16_t* __restrict__ Bm) {
  __shared__ bf16_t As[128 * 32];
  __shared__ bf16_t Bs[128 * 32];
  int m0 = blockIdx.x * 128;
  int n0 = blockIdx.y * 128;
  int tid = threadIdx.x;
  int w = tid >> 6, L = tid & 63, l15 = L & 15, q4 = L >> 4;
  int wm = w >> 1, wn = w & 1;
  f32x4 acc[4][4] = {};
  for (int k0 = 0; k0 < 128; k0 += 32) {
#pragma unroll
    for (int rep = 0; rep < 2; ++rep) {
      int idx = tid + rep * 256;
      int row = idx >> 2, sg = idx & 3;
      *(uint4_a*)&As[row * 32 + sg * 8] = *(const uint4_a*)(A + (size_t)(m0 + row) * 128 + k0 + sg * 8);
      *(uint4_a*)&Bs[row * 32 + sg * 8] = *(const uint4_a*)(B + (size_t)(n0 + row) * 128 + k0 + sg * 8);
    }
    __syncthreads();
    bf16x8 af[4], bfr[4];
#pragma unroll
    for (int mt = 0; mt < 4; ++mt) af[mt] = *(const bf16x8_a*)&As[(wm * 64 + mt * 16 + l15) * 32 + q4 * 8];
#pragma unroll
    for (int nt = 0; nt < 4; ++nt) bfr[nt] = *(const bf16x8_a*)&Bs[(wn * 64 + nt * 16 + l15) * 32 + q4 * 8];
#pragma unroll
    for (int mt = 0; mt < 4; ++mt)
#pragma unroll
      for (int nt = 0; nt < 4; ++nt) acc[mt][nt] = MFMA16(af[mt], bfr[nt], acc[mt][nt]);
    __syncthreads();
  }
#pragma unroll
  for (int mt = 0; mt < 4; ++mt)
#pragma unroll
    for (int i = 0; i < 4; ++i) {
      int m = m0 + wm * 64 + mt * 16 + q4 * 4 + i;
      float mp = mu[m], rp = rstd[m];
#pragma unroll
      for (int nt = 0; nt < 4; ++nt) {
        int n = n0 + wn * 64 + nt * 16 + l15;
        float val = rp * (acc[mt][nt][i] - mp * sw[n]) + beta[n];
        Bm[(size_t)m * kS + n] = f2bf(val);
      }
    }
}

// ---------------- fused attention: bias-preload + QK^T + softmax(r) + PV ----------------
// grid (2, kS): blockIdx.x = t-half, blockIdx.y = s. 256 threads / 4 waves.
// Wave w owns t in [192*tb + 48w, +48): scores acc[24 r-tiles][3 t-tiles] in regs.
// Softmax over r is wave-local. PV contracts the block's 192-t half -> raw partial
// written to opart (tb=0 -> d_out, tb=1 -> pB); gating+combine happen in final GEMM.
__global__ __launch_bounds__(256, 1) void k_attn(const bf16_t* __restrict__ q,
                                                 const bf16_t* __restrict__ kmat,
                                                 const bf16_t* __restrict__ v,
                                                 const bf16_t* __restrict__ Bm,
                                                 float* __restrict__ o0,
                                                 float* __restrict__ o1,
                                                 int head) {
  int tb = blockIdx.x;
  int s  = blockIdx.y;
  int tid = threadIdx.x;
  int w = tid >> 6, L = tid & 63, l15 = L & 15, q4 = L >> 4;
  float* opart = tb ? o1 : o0;
  __shared__ bf16_t vT[32 * 200];   // [c][t_loc], padded stride 200
  __shared__ bf16_t Psh[64 * 192];  // probs chunk, XOR-swizzled rows

  int tbase = tb * 192;
  // ---- stage V^T for this t-half ----
#pragma unroll
  for (int rep = 0; rep < 3; ++rep) {
    int idx = tid + rep * 256;  // 768 = 192 t * 4 sg
    int t = idx >> 2, sg = idx & 3;
    union { uint4 u; bf16_t h[8]; } uu;
    uu.u = *(const uint4_a*)(v + (size_t)(s * kR + tbase + t) * kC + sg * 8);
#pragma unroll
    for (int j = 0; j < 8; ++j) vT[(sg * 8 + j) * 200 + t] = uu.h[j];
  }
  __syncthreads();
  // ---- V fragments for PV (held in regs for all 6 chunks) ----
  bf16x8 bfv[12];
#pragma unroll
  for (int kk = 0; kk < 6; ++kk)
#pragma unroll
    for (int ct = 0; ct < 2; ++ct)
      bfv[kk * 2 + ct] = *(const bf16x8_a*)&vT[(ct * 16 + l15) * 200 + kk * 32 + q4 * 8];

  // ---- bias preload into acc (bias pre-scaled by 1/sqrt(c) upstream) ----
  int t0 = tbase + 48 * w;
  const bf16_t* bmS = Bm + (size_t)s * kP;
  f32x4 acc[24][3];
#pragma unroll
  for (int rt = 0; rt < 24; ++rt)
#pragma unroll
    for (int tt = 0; tt < 3; ++tt)
#pragma unroll
      for (int i = 0; i < 4; ++i)
        acc[rt][tt][i] = bf2f(bmS[(size_t)(rt * 16 + q4 * 4 + i) * kR + t0 + tt * 16 + l15]);

  // ---- QK^T (q pre-scaled) ----
  const bf16_t* qs = q + (size_t)s * kR * kC;
  const bf16_t* kp = kmat + (size_t)s * kR * kC;
  bf16x8 bk[3];
#pragma unroll
  for (int tt = 0; tt < 3; ++tt)
    bk[tt] = *(const bf16x8_a*)(kp + (size_t)(t0 + tt * 16 + l15) * kC + q4 * 8);
#pragma unroll
  for (int rt = 0; rt < 24; ++rt) {
    bf16x8 af = *(const bf16x8_a*)(qs + (size_t)(rt * 16 + l15) * kC + q4 * 8);
#pragma unroll
    for (int tt = 0; tt < 3; ++tt) acc[rt][tt] = MFMA16(af, bk[tt], acc[rt][tt]);
  }

  // ---- softmax over r (wave-local: in-thread 24x4, then q4 butterfly) ----
  float mx[3] = {-3.0e38f, -3.0e38f, -3.0e38f};
#pragma unroll
  for (int rt = 0; rt < 24; ++rt)
#pragma unroll
    for (int tt = 0; tt < 3; ++tt)
#pragma unroll
      for (int i = 0; i < 4; ++i) mx[tt] = fmaxf(mx[tt], acc[rt][tt][i]);
#pragma unroll
  for (int tt = 0; tt < 3; ++tt) {
    mx[tt] = fmaxf(mx[tt], __shfl_xor(mx[tt], 16));
    mx[tt] = fmaxf(mx[tt], __shfl_xor(mx[tt], 32));
  }
  float sm[3] = {0.f, 0.f, 0.f};
#pragma unroll
  for (int rt = 0; rt < 24; ++rt)
#pragma unroll
    for (int tt = 0; tt < 3; ++tt)
#pragma unroll
      for (int i = 0; i < 4; ++i) {
        float e = __expf(acc[rt][tt][i] - mx[tt]);
        acc[rt][tt][i] = e;
        sm[tt] += e;
      }
#pragma unroll
  for (int tt = 0; tt < 3; ++tt) {
    sm[tt] += __shfl_xor(sm[tt], 16);
    sm[tt] += __shfl_xor(sm[tt], 32);
  }
  float di[3];
#pragma unroll
  for (int tt = 0; tt < 3; ++tt) di[tt] = 1.0f / sm[tt];

  // ---- PV in 6 chunks of 64 r-rows through swizzled LDS ----
#pragma unroll
  for (int c = 0; c < 6; ++c) {
#pragma unroll
    for (int j = 0; j < 4; ++j)
#pragma unroll
      for (int tt = 0; tt < 3; ++tt)
#pragma unroll
        for (int i = 0; i < 4; ++i) {
          int rl = j * 16 + q4 * 4 + i;
          int tl = 48 * w + tt * 16 + l15;
          Psh[rl * 192 + (tl ^ ((rl & 7) << 3))] = f2bf(acc[4 * c + j][tt][i] * di[tt]);
        }
    __syncthreads();
    f32x4 pacc[2] = {};
    int rr = w * 16 + l15;
#pragma unroll
    for (int kk = 0; kk < 6; ++kk) {
      int e = kk * 32 + q4 * 8;
      bf16x8 af = *(const bf16x8_a*)&Psh[rr * 192 + (e ^ ((rr & 7) << 3))];
#pragma unroll
      for (int ct = 0; ct < 2; ++ct) pacc[ct] = MFMA16(af, bfv[kk * 2 + ct], pacc[ct]);
    }
#pragma unroll
    for (int ct = 0; ct < 2; ++ct)
#pragma unroll
      for (int i = 0; i < 4; ++i) {
        int r = c * 64 + w * 16 + q4 * 4 + i;
        int cc = ct * 16 + l15;
        opart[(size_t)(s * kR + r) * kCM + head * kC + cc] = pacc[ct][i];
      }
    __syncthreads();
  }
}

// ---------------- final GEMM: A=(pA+pB)*g (fp32->hi/lo bf16) x (256 x 256)^T, in-place d_out --------
__global__ __launch_bounds__(256) void k_gemm_final_mx(const float* __restrict__ pA,
                                                       const float* __restrict__ pB,
                                                       const bf16_t* __restrict__ gall,
                                                       const bf16_t* __restrict__ Bw,
                                                       const float* __restrict__ bias,
                                                       float* __restrict__ out) {
  __shared__ bf16_t As[2 * 64 * 32];  // [half][row][k]
  __shared__ bf16_t Bs[256 * 32];
  int m0 = blockIdx.x * 64;
  int tid = threadIdx.x;
  int w = tid >> 6, L = tid & 63, l15 = L & 15, q4 = L >> 4;
  f32x4 acc[4][4] = {};  // [mt][nt]
  for (int kc = 0; kc < 256; kc += 32) {
    {
      int row = tid >> 2, sg = tid & 3;
      size_t base = (size_t)(m0 + row) * kCM + kc + sg * 8;
      float4_a a0 = *(const float4_a*)(pA + base);
      float4_a a1 = *(const float4_a*)(pA + base + 4);
      float4_a b0 = *(const float4_a*)(pB + base);
      float4_a b1 = *(const float4_a*)(pB + base + 4);
      union { bf16x8 v; bf16_t h[8]; } gg;
      gg.v = *(const bf16x8_a*)(gall + base);
      float ff[8] = {a0.x + b0.x, a0.y + b0.y, a0.z + b0.z, a0.w + b0.w,
                     a1.x + b1.x, a1.y + b1.y, a1.z + b1.z, a1.w + b1.w};
#pragma unroll
      for (int j = 0; j < 8; ++j) ff[j] *= bf2f(gg.h[j]);
      uint4 uh, ul;
      bf16_t hi[8], lo[8];
#pragma unroll
      for (int j = 0; j < 8; ++j) {
        hi[j] = f2bf(ff[j]);
        lo[j] = f2bf(ff[j] - bf2f(hi[j]));
      }
      uh.x = (unsigned)hi[0] | ((unsigned)hi[1] << 16); uh.y = (unsigned)hi[2] | ((unsigned)hi[3] << 16);
      uh.z = (unsigned)hi[4] | ((unsigned)hi[5] << 16); uh.w = (unsigned)hi[6] | ((unsigned)hi[7] << 16);
      ul.x = (unsigned)lo[0] | ((unsigned)lo[1] << 16); ul.y = (unsigned)lo[2] | ((unsigned)lo[3] << 16);
      ul.z = (unsigned)lo[4] | ((unsigned)lo[5] << 16); ul.w = (unsigned)lo[6] | ((unsigned)lo[7] << 16);
      *(uint4_a*)&As[row * 32 + sg * 8] = uh;
      *(uint4_a*)&As[2048 + row * 32 + sg * 8] = ul;
    }
#pragma unroll
    for (int rep = 0; rep < 4; ++rep) {
      int idx = tid + rep * 256;
      int row = idx >> 2, sg = idx & 3;
      *(uint4_a*)&Bs[row * 32 + sg * 8] = *(const uint4_a*)(Bw + (size_t)row * kCM + kc + sg * 8);
    }
    __syncthreads();
    bf16x8 bfr[4];
#pragma unroll
    for (int nt = 0; nt < 4; ++nt) bfr[nt] = *(const bf16x8_a*)&Bs[(w * 64 + nt * 16 + l15) * 32 + q4 * 8];
#pragma unroll
    for (int half = 0; half < 2; ++half)
#pragma unroll
      for (int mt = 0; mt < 4; ++mt) {
        bf16x8 af = *(const bf16x8_a*)&As[half * 2048 + (mt * 16 + l15) * 32 + q4 * 8];
#pragma unroll
        for (int nt = 0; nt < 4; ++nt) acc[mt][nt] = MFMA16(af, bfr[nt], acc[mt][nt]);
      }
    __syncthreads();
  }
#pragma unroll
  for (int mt = 0; mt < 4; ++mt)
#pragma unroll
    for (int nt = 0; nt < 4; ++nt) {
      int n = w * 64 + nt * 16 + l15;
      float bn = bias[n];
#pragma unroll
      for (int i = 0; i < 4; ++i) {
        int m = m0 + mt * 16 + q4 * 4 + i;
        out[(size_t)m * kCM + n] = acc[mt][nt][i] + bn;
      }
    }
}

extern "C" void kernel_launch(void* const* d_in, const int* in_sizes, int n_in,
                              void* d_out, int out_size, void* d_ws, size_t ws_size,
                              hipStream_t stream) {
  (void)in_sizes; (void)n_in; (void)out_size; (void)ws_size;
  const float* msa_in = (const float*)d_in[0];
  const float* pair   = (const float*)d_in[1];
  const float* nmw    = (const float*)d_in[2];
  const float* nmb    = (const float*)d_in[3];
  const float* wq     = (const float*)d_in[4];
  const float* wk     = (const float*)d_in[5];
  const float* wv     = (const float*)d_in[6];
  const float* npw    = (const float*)d_in[7];
  const float* npb    = (const float*)d_in[8];
  const float* wb     = (const float*)d_in[9];
  const float* wg     = (const float*)d_in[10];
  const float* outw   = (const float*)d_in[11];
  const float* outb   = (const float*)d_in[12];
  float* out = (float*)d_out;

  char* ws = (char*)d_ws;
  size_t off = 0;
  bf16_t* msa_cur  = (bf16_t*)(ws + off); off += (size_t)kM * kCM * 2;    // 50,331,648
  bf16_t* pair_bf  = (bf16_t*)(ws + off); off += (size_t)kP * kCZ * 2;    // 37,748,736
  bf16_t* Bm       = (bf16_t*)(ws + off); off += (size_t)kP * kS * 2;     // 75,497,472
  bf16_t* qb       = (bf16_t*)(ws + off); off += (size_t)kM * kC * 2;     // 6,291,456
  bf16_t* kb       = (bf16_t*)(ws + off); off += (size_t)kM * kC * 2;
  bf16_t* vb       = (bf16_t*)(ws + off); off += (size_t)kM * kC * 2;
  bf16_t* g_all    = (bf16_t*)(ws + off); off += (size_t)kM * kCM * 2;    // 50,331,648
  float*  pB       = (float*)(ws + off);  off += (size_t)kM * kCM * 4;    // 100,663,296
  float* mu_p      = (float*)(ws + off);  off += (size_t)kP * 4;          // 589,824
  float* rstd_p    = (float*)(ws + off);  off += (size_t)kP * 4;
  bf16_t* Wcat_all = (bf16_t*)(ws + off); off += (size_t)kH * 128 * 256 * 2;
  bf16_t* wbef_all = (bf16_t*)(ws + off); off += (size_t)kH * 256 * 128 * 2;
  bf16_t* outw_bf  = (bf16_t*)(ws + off); off += (size_t)256 * 256 * 2;
  float* beta_all  = (float*)(ws + off);  off += (size_t)kH * 256 * 4;
  float* sw_all    = (float*)(ws + off);  off += (size_t)kH * 256 * 4;
  // total ~335 MB (d_out doubles as partial-O buffer A)

  // setup (off the per-head critical path)
  k_pair_fused<<<kP / 8, 256, 0, stream>>>(pair, pair_bf, mu_p, rstd_p);
  k_pack_outw<<<256, 256, 0, stream>>>(outw, outw_bf);
  k_pack_wcat_all<<<kH * 128, 256, 0, stream>>>(wq, wk, wv, wg, Wcat_all);
  k_pack_bias_all<<<kH, 256, 0, stream>>>(wb, npw, npb, wbef_all, beta_all, sw_all);

  for (int h = 0; h < kH; ++h) {
    k_msa_ln<<<kM / 8, 256, 0, stream>>>(msa_in, msa_cur, msa_cur, nmw, nmb, h, h == 0 ? 1 : 0);
    k_gemm_qkvg_mx<<<kM / 128, 256, 0, stream>>>(msa_cur, Wcat_all + (size_t)h * 128 * 256,
                                                 qb, kb, vb, g_all, h);
    k_gemm_bias_mx<<<dim3(kP / 128, 2), 256, 0, stream>>>(pair_bf, wbef_all + (size_t)h * 256 * 128,
                                                          mu_p, rstd_p,
                                                          sw_all + h * 256, beta_all + h * 256, Bm);
    k_attn<<<dim3(2, kS), 256, 0, stream>>>(qb, kb, vb, Bm, out, pB, h);
  }

  k_gemm_final_mx<<<kM / 64, 256, 0, stream>>>(out, pB, g_all, outw_bf, outb, out);
}